// Round 9
// baseline (303.187 us; speedup 1.0000x reference)
//
#include <hip/hip_runtime.h>

typedef float f32x4 __attribute__((ext_vector_type(4)));
typedef short bf16x8 __attribute__((ext_vector_type(8)));
typedef unsigned short u16;

namespace {

constexpr int Nn = 64, Tt = 300, Vv = 25;
constexpr float EPSf = 1e-5f;

__device__ __forceinline__ u16 f2bu(float f) {
  union { float f; unsigned int i; } c; c.f = f;
  unsigned int r = c.i + 0x7fffu + ((c.i >> 16) & 1u);   // RNE
  return (u16)(r >> 16);
}

// ---------------------------------------------------------------------------
// prep: blocks 0..63 -> per-n AT (padded, transposed, bf16) + bias2d table
//                       + copy A to output tail
//       block 64     -> wT + folded BN coefficients
//       blocks 65..73 -> w2T for kt = b-65
// ---------------------------------------------------------------------------
__global__ __launch_bounds__(256) void prep(
    const float* __restrict__ A, const float* __restrict__ Wc, const float* __restrict__ bc,
    const float* __restrict__ g1, const float* __restrict__ b1,
    const float* __restrict__ m1, const float* __restrict__ v1,
    const float* __restrict__ tcw, const float* __restrict__ tb,
    const float* __restrict__ g2, const float* __restrict__ b2,
    const float* __restrict__ m2, const float* __restrict__ v2,
    u16* __restrict__ atk, u16* __restrict__ wt, u16* __restrict__ w2t,
    float* __restrict__ invadd, float* __restrict__ bias2d,
    float* __restrict__ outA)
{
  const int b = blockIdx.x, tid = threadIdx.x;
  if (b < 64) {
    __shared__ float Al[1875];
    __shared__ float SAl[75];
    const float* An = A + b * 1875;
    for (int e = tid; e < 1875; e += 256) Al[e] = An[e];
    __syncthreads();
    if (tid < 75) {
      int k = tid / 25, w = tid % 25;
      float s = 0.f;
      for (int v = 0; v < 25; ++v) s += Al[k * 625 + v * 25 + w];
      SAl[tid] = s;
    }
    // A -> output tail (tuple output (out, A))
    for (int e = tid; e < 1875; e += 256) outA[b * 1875 + e] = Al[e];
    __syncthreads();
    // AT[k][w(32)][v(32)] = A[n][k][v][w], zero-padded
    for (int e = tid; e < 3072; e += 256) {
      int k = e >> 10, r = e & 1023, w = r >> 5, v = r & 31;
      float val = (v < 25 && w < 25) ? Al[k * 625 + v * 25 + w] : 0.f;
      atk[b * 3072 + e] = f2bu(val);
    }
    // bias2d[n][c][w] = sum_k bc[k*64+c] * SA[k][w]
    for (int e = tid; e < 1600; e += 256) {
      int c = e / 25, w = e % 25;
      bias2d[b * 1600 + e] = bc[c] * SAl[w] + bc[64 + c] * SAl[25 + w] + bc[128 + c] * SAl[50 + w];
    }
  } else if (b == 64) {
    // wT[c][r=k*64+ci] = conv_w[k*64+c][ci]
    for (int e = tid; e < 12288; e += 256) {
      int c = e / 192, r = e - c * 192, k = r >> 6, ci = r & 63;
      wt[e] = f2bu(Wc[(k * 64 + c) * 64 + ci]);
    }
    if (tid < 64) {
      int c = tid;
      float i1 = g1[c] * rsqrtf(v1[c] + EPSf);
      float a1 = b1[c] - m1[c] * i1;
      float i2 = g2[c] * rsqrtf(v2[c] + EPSf);
      float a2 = b2[c] - m2[c] * i2 + tb[c] * i2;
      invadd[c] = i1; invadd[64 + c] = a1; invadd[128 + c] = i2; invadd[192 + c] = a2;
    }
  } else {
    // w2T[kt][co][ci] = tconv_w[co][ci][kt], one kt per block
    const int kt = b - 65;
    for (int i = tid; i < 4096; i += 256) {
      int co = i >> 6, ci = i & 63;
      w2t[kt * 4096 + i] = f2bu(tcw[(co * 64 + ci) * 9 + kt]);
    }
  }
}

// ---------------------------------------------------------------------------
// K1: fused GCN via MFMA. grid (50, 64), 512 threads = 8 waves, 6-t tile.
// Same geometry/swizzles as the proven 256-thread version; 8 waves share the
// LDS tile so per-wave work halves and occupancy doubles (16 waves/CU).
// Weights (Af[6][4]) stay fully VGPR-resident -> zero global loads in the
// stage-2 accumulation loop.
// ---------------------------------------------------------------------------
__global__ __launch_bounds__(512, 4) void k1_gcn(
    const float* __restrict__ x, const u16* __restrict__ atk, const u16* __restrict__ wt,
    const float* __restrict__ invadd, const float* __restrict__ bias2d,
    u16* __restrict__ zT)
{
  __shared__ __align__(16) u16 xaT[160 * 192];
  __shared__ float bias_l[1600];

  const int tid = threadIdx.x;
  const int tt = blockIdx.x, n = blockIdx.y;
  const int t0 = tt * 6;
  const int w = tid >> 6, l = tid & 63, lq = l & 15, g = l >> 4;

  for (int e = tid; e < 1600; e += 512) bias_l[e] = bias2d[n * 1600 + e];
  for (int e = tid; e < 10 * 192; e += 512) xaT[150 * 192 + e] = 0;  // tail rows -> 0

  // hoisted stage-1 B-frags: B[v][w] stored AT[w][v]
  bf16x8 Bf[3][2];
  #pragma unroll
  for (int k = 0; k < 3; ++k)
    #pragma unroll
    for (int nt = 0; nt < 2; ++nt)
      Bf[k][nt] = *(const bf16x8*)(atk + ((size_t)(n * 3 + k) * 32 + nt * 16 + lq) * 32 + g * 8);

  // preloaded stage-2 A-frags (weights): removes global loads from acc loop
  bf16x8 Af[6][4];
  #pragma unroll
  for (int kc = 0; kc < 6; ++kc)
    #pragma unroll
    for (int ct = 0; ct < 4; ++ct)
      Af[kc][ct] = *(const bf16x8*)(wt + (ct * 16 + lq) * 192 + kc * 32 + g * 8);

  // ---- stage 1: 24 M-tiles (6 t x 4 ci-tiles), wave w takes mt = w+8i ----
  f32x4 xc0, xc1;
  {
    const int mt = w;
    const int tl = mt >> 2, ci0 = (mt & 3) << 4;
    const float* xr = x + ((size_t)(n * 64 + ci0 + lq) * Tt + t0 + tl) * Vv;
    __builtin_memcpy(&xc0, xr + g * 8, 16);
    __builtin_memcpy(&xc1, xr + g * 8 + 4, 16);
  }
  #pragma unroll 1
  for (int i = 0; i < 3; ++i) {
    f32x4 xn0, xn1;
    if (i < 2) {
      const int mtn = w + 8 * (i + 1);
      const int tln = mtn >> 2, ci0n = (mtn & 3) << 4;
      const float* xrn = x + ((size_t)(n * 64 + ci0n + lq) * Tt + t0 + tln) * Vv;
      __builtin_memcpy(&xn0, xrn + g * 8, 16);
      __builtin_memcpy(&xn1, xrn + g * 8 + 4, 16);
    }
    const int mt = w + 8 * i;
    const int tl = mt >> 2, ci0 = (mt & 3) << 4;
    bf16x8 a;
    if (g < 3) {
      a[0] = (short)f2bu(xc0[0]); a[1] = (short)f2bu(xc0[1]);
      a[2] = (short)f2bu(xc0[2]); a[3] = (short)f2bu(xc0[3]);
      a[4] = (short)f2bu(xc1[0]); a[5] = (short)f2bu(xc1[1]);
      a[6] = (short)f2bu(xc1[2]); a[7] = (short)f2bu(xc1[3]);
    } else {
      a[0] = (short)f2bu(xc0[0]);     // element v=24
      a[1] = 0; a[2] = 0; a[3] = 0; a[4] = 0; a[5] = 0; a[6] = 0; a[7] = 0;
    }
    #pragma unroll
    for (int k = 0; k < 3; ++k)
      #pragma unroll
      for (int nt = 0; nt < 2; ++nt) {
        f32x4 acc = {0.f, 0.f, 0.f, 0.f};
        acc = __builtin_amdgcn_mfma_f32_16x16x32_bf16(a, Bf[k][nt], acc, 0, 0, 0);
        const int wcol = nt * 16 + lq;
        if (wcol < 25) {
          const int twl = tl * 25 + wcol;
          ushort4 s;
          s.x = f2bu(acc[0]); s.y = f2bu(acc[1]); s.z = f2bu(acc[2]); s.w = f2bu(acc[3]);
          const int byte = twl * 384 + ((k * 128 + ci0 * 2 + g * 8) ^ ((twl & 7) << 4));
          *(ushort4*)((char*)xaT + byte) = s;
        }
      }
    xc0 = xn0; xc1 = xn1;
  }
  __syncthreads();

  // ---- stage 2: D[c][tw] ; 10 tw-tiles over 8 waves: ni in {w, w+8} ----
  f32x4 acc2[2][4];
  #pragma unroll
  for (int ni = 0; ni < 2; ++ni)
    #pragma unroll
    for (int ct = 0; ct < 4; ++ct) acc2[ni][ct] = (f32x4){0.f, 0.f, 0.f, 0.f};
  const int nvalid = (w < 2) ? 2 : 1;

  #pragma unroll
  for (int kc = 0; kc < 6; ++kc) {
    #pragma unroll
    for (int ni = 0; ni < 2; ++ni) {
      if (ni < nvalid) {
        const int row = (w + 8 * ni) * 16 + lq;
        const int byte = row * 384 + ((kc * 64 + g * 16) ^ ((row & 7) << 4));
        const bf16x8 Bv = *(const bf16x8*)((const char*)xaT + byte);
        #pragma unroll
        for (int ct = 0; ct < 4; ++ct)
          acc2[ni][ct] = __builtin_amdgcn_mfma_f32_16x16x32_bf16(Af[kc][ct], Bv, acc2[ni][ct], 0, 0, 0);
      }
    }
  }

  #pragma unroll
  for (int ni = 0; ni < 2; ++ni) {
    if (ni < nvalid) {
      const int twl = (w + 8 * ni) * 16 + lq;
      if (twl < 150) {
        const int wcol = twl % 25;
        const int tvg = tt * 150 + twl;
        #pragma unroll
        for (int ct = 0; ct < 4; ++ct) {
          const int c0 = ct * 16 + g * 4;
          const f32x4 iv = *(const f32x4*)(invadd + c0);
          const f32x4 av = *(const f32x4*)(invadd + 64 + c0);
          ushort4 s;
          float z0 = (acc2[ni][ct][0] + bias_l[(c0 + 0) * 25 + wcol]) * iv[0] + av[0];
          float z1 = (acc2[ni][ct][1] + bias_l[(c0 + 1) * 25 + wcol]) * iv[1] + av[1];
          float z2 = (acc2[ni][ct][2] + bias_l[(c0 + 2) * 25 + wcol]) * iv[2] + av[2];
          float z3 = (acc2[ni][ct][3] + bias_l[(c0 + 3) * 25 + wcol]) * iv[3] + av[3];
          s.x = f2bu(fmaxf(z0, 0.f)); s.y = f2bu(fmaxf(z1, 0.f));
          s.z = f2bu(fmaxf(z2, 0.f)); s.w = f2bu(fmaxf(z3, 0.f));
          *(ushort4*)(zT + ((size_t)n * 7500 + tvg) * 64 + c0) = s;
        }
      }
    }
  }
}

// ---------------------------------------------------------------------------
// K2: fused TCN via MFMA. grid (25, 64), 512 threads = 8 waves, 12-t tile.
// Wave ownership: co-tile ct = w&3, M-half h = w>>2 (10 / 9 M-tiles).
// Per kc phase (2): preload 9 weight B-frags to VGPR (STATIC indexing —
// both kt loops fully unrolled, rule #20), then 9x10 pure
// {ds_read_b128 + MFMA} with zero global/scratch traffic.
// out = relu(bn2(conv) + x).
// ---------------------------------------------------------------------------
__global__ __launch_bounds__(512, 4) void k2_tcn(
    const u16* __restrict__ zT, const u16* __restrict__ w2t,
    const float* __restrict__ invadd, const float* __restrict__ x,
    float* __restrict__ out)
{
  __shared__ __align__(16) u16 win[512 * 64];

  const int tid = threadIdx.x;
  const int tt = blockIdx.x, n = blockIdx.y;
  const int t0 = tt * 12;
  const int w = tid >> 6, l = tid & 63, lq = l & 15, g = l >> 4;
  const int ct = w & 3, h = w >> 2;
  const int co0 = ct * 16;
  const int tvbase = t0 * 25 - 100;

  // stage window (512 rows x 64 ch), swizzled, 8 exact iters
  #pragma unroll
  for (int it = 0; it < 8; ++it) {
    const int f = tid + it * 512;
    const int lrow = f >> 3, c16 = f & 7;
    const int tv = tvbase + lrow;
    bf16x8 val = {0, 0, 0, 0, 0, 0, 0, 0};
    if (tv >= 0 && tv < 7500)
      val = *(const bf16x8*)(zT + ((size_t)n * 7500 + tv) * 64 + c16 * 8);
    const int byte = lrow * 128 + ((c16 * 16) ^ ((lrow & 7) << 4));
    *(bf16x8*)((char*)win + byte) = val;
  }
  __syncthreads();

  const int nj = h ? 9 : 10;          // M-tiles: h=0 -> 0..9, h=1 -> 10..18
  f32x4 acc[10];
  #pragma unroll
  for (int j = 0; j < 10; ++j) acc[j] = (f32x4){0.f, 0.f, 0.f, 0.f};

  #pragma unroll 1
  for (int kc = 0; kc < 2; ++kc) {
    bf16x8 wf[9];
    #pragma unroll
    for (int kt = 0; kt < 9; ++kt)
      wf[kt] = *(const bf16x8*)(w2t + (size_t)(kt * 64 + co0 + lq) * 64 + kc * 32 + g * 8);
    #pragma unroll
    for (int kt = 0; kt < 9; ++kt) {     // FULLY unrolled: wf[kt] static -> VGPR
      #pragma unroll
      for (int j = 0; j < 10; ++j) {
        if (j < nj) {
          const int mt = h * 10 + j;
          const int lrow = mt * 16 + lq + kt * 25;
          const int byte = lrow * 128 + ((kc * 64 + g * 16) ^ ((lrow & 7) << 4));
          const bf16x8 Av = *(const bf16x8*)((const char*)win + byte);
          acc[j] = __builtin_amdgcn_mfma_f32_16x16x32_bf16(Av, wf[kt], acc[j], 0, 0, 0);
        }
      }
    }
  }

  // epilogue: +bn2 + residual + relu
  const float i2 = invadd[128 + co0 + lq];
  const float a2 = invadd[192 + co0 + lq];
  #pragma unroll
  for (int j = 0; j < 10; ++j) {
    if (j < nj) {
      const int mt = h * 10 + j;
      const int tvl0 = mt * 16 + g * 4;
      if (tvl0 < 300) {
        const size_t base = (size_t)(n * 64 + co0 + lq) * 7500 + t0 * 25 + tvl0;
        const f32x4 xv = *(const f32x4*)(x + base);
        f32x4 o;
        #pragma unroll
        for (int r = 0; r < 4; ++r)
          o[r] = fmaxf(acc[j][r] * i2 + a2 + xv[r], 0.f);
        *(f32x4*)(out + base) = o;
      }
    }
  }
}

} // namespace

extern "C" void kernel_launch(void* const* d_in, const int* in_sizes, int n_in,
                              void* d_out, int out_size, void* d_ws, size_t ws_size,
                              hipStream_t stream)
{
  const float* x  = (const float*)d_in[0];
  const float* A  = (const float*)d_in[1];
  const float* Wc = (const float*)d_in[2];
  const float* bc = (const float*)d_in[3];
  const float* g1 = (const float*)d_in[4];
  const float* b1 = (const float*)d_in[5];
  const float* m1 = (const float*)d_in[6];
  const float* v1 = (const float*)d_in[7];
  const float* tw = (const float*)d_in[8];
  const float* tb = (const float*)d_in[9];
  const float* g2 = (const float*)d_in[10];
  const float* b2 = (const float*)d_in[11];
  const float* m2 = (const float*)d_in[12];
  const float* v2 = (const float*)d_in[13];
  float* out = (float*)d_out;

  char* ws = (char*)d_ws;
  u16*   zT     = (u16*)(ws);                        // 61,440,000 B
  u16*   atk    = (u16*)(ws + 61440000);             //    393,216 B
  u16*   wt     = (u16*)(ws + 61833216);             //     24,576 B
  u16*   w2t    = (u16*)(ws + 61857792);             //     73,728 B
  float* invadd = (float*)(ws + 61931520);           //      1,024 B
  float* bias2d = (float*)(ws + 61932544);           //    409,600 B

  prep<<<dim3(74), dim3(256), 0, stream>>>(A, Wc, bc, g1, b1, m1, v1, tw, tb,
                                           g2, b2, m2, v2, atk, wt, w2t, invadd, bias2d,
                                           out + 30720000);
  k1_gcn<<<dim3(50, 64), dim3(512), 0, stream>>>(x, atk, wt, invadd, bias2d, zT);
  k2_tcn<<<dim3(25, 64), dim3(512), 0, stream>>>(zT, w2t, invadd, x, out);
}

// Round 10
// 188.673 us; speedup vs baseline: 1.6069x; 1.6069x over previous
//
#include <hip/hip_runtime.h>

typedef float f32x4 __attribute__((ext_vector_type(4)));
typedef short bf16x8 __attribute__((ext_vector_type(8)));
typedef unsigned short u16;

namespace {

constexpr int Nn = 64, Tt = 300, Vv = 25;
constexpr float EPSf = 1e-5f;

__device__ __forceinline__ u16 f2bu(float f) {
  union { float f; unsigned int i; } c; c.f = f;
  unsigned int r = c.i + 0x7fffu + ((c.i >> 16) & 1u);   // RNE
  return (u16)(r >> 16);
}

// ---------------------------------------------------------------------------
// prep: blocks 0..63 -> per-n AT (padded, transposed, bf16) + bias2d table
//                       + copy A to output tail
//       block 64     -> wT + folded BN coefficients
//       blocks 65..73 -> w2T for kt = b-65
// ---------------------------------------------------------------------------
__global__ __launch_bounds__(256) void prep(
    const float* __restrict__ A, const float* __restrict__ Wc, const float* __restrict__ bc,
    const float* __restrict__ g1, const float* __restrict__ b1,
    const float* __restrict__ m1, const float* __restrict__ v1,
    const float* __restrict__ tcw, const float* __restrict__ tb,
    const float* __restrict__ g2, const float* __restrict__ b2,
    const float* __restrict__ m2, const float* __restrict__ v2,
    u16* __restrict__ atk, u16* __restrict__ wt, u16* __restrict__ w2t,
    float* __restrict__ invadd, float* __restrict__ bias2d,
    float* __restrict__ outA)
{
  const int b = blockIdx.x, tid = threadIdx.x;
  if (b < 64) {
    __shared__ float Al[1875];
    __shared__ float SAl[75];
    const float* An = A + b * 1875;
    for (int e = tid; e < 1875; e += 256) Al[e] = An[e];
    __syncthreads();
    if (tid < 75) {
      int k = tid / 25, w = tid % 25;
      float s = 0.f;
      for (int v = 0; v < 25; ++v) s += Al[k * 625 + v * 25 + w];
      SAl[tid] = s;
    }
    // A -> output tail (tuple output (out, A))
    for (int e = tid; e < 1875; e += 256) outA[b * 1875 + e] = Al[e];
    __syncthreads();
    // AT[k][w(32)][v(32)] = A[n][k][v][w], zero-padded
    for (int e = tid; e < 3072; e += 256) {
      int k = e >> 10, r = e & 1023, w = r >> 5, v = r & 31;
      float val = (v < 25 && w < 25) ? Al[k * 625 + v * 25 + w] : 0.f;
      atk[b * 3072 + e] = f2bu(val);
    }
    // bias2d[n][c][w] = sum_k bc[k*64+c] * SA[k][w]
    for (int e = tid; e < 1600; e += 256) {
      int c = e / 25, w = e % 25;
      bias2d[b * 1600 + e] = bc[c] * SAl[w] + bc[64 + c] * SAl[25 + w] + bc[128 + c] * SAl[50 + w];
    }
  } else if (b == 64) {
    // wT[c][r=k*64+ci] = conv_w[k*64+c][ci]
    for (int e = tid; e < 12288; e += 256) {
      int c = e / 192, r = e - c * 192, k = r >> 6, ci = r & 63;
      wt[e] = f2bu(Wc[(k * 64 + c) * 64 + ci]);
    }
    if (tid < 64) {
      int c = tid;
      float i1 = g1[c] * rsqrtf(v1[c] + EPSf);
      float a1 = b1[c] - m1[c] * i1;
      float i2 = g2[c] * rsqrtf(v2[c] + EPSf);
      float a2 = b2[c] - m2[c] * i2 + tb[c] * i2;
      invadd[c] = i1; invadd[64 + c] = a1; invadd[128 + c] = i2; invadd[192 + c] = a2;
    }
  } else {
    // w2T[kt][co][ci] = tconv_w[co][ci][kt], one kt per block
    const int kt = b - 65;
    for (int i = tid; i < 4096; i += 256) {
      int co = i >> 6, ci = i & 63;
      w2t[kt * 4096 + i] = f2bu(tcw[(co * 64 + ci) * 9 + kt]);
    }
  }
}

// ---------------------------------------------------------------------------
// K1: fused GCN via MFMA. grid (50, 64), 512 threads = 8 waves, 6-t tile.
// stage1: wave w owns 3 M-tiles (mt = w+8i): xaT[tw][k*64+ci] (LDS, swizzled)
// stage2: wave = (co-tile ct=w&3, half h=w>>2); only 6 own-ct weight frags
//         in VGPR (24 regs), acc[5] -> ~100 VGPR total, NO spill.
// epilogue: z' = relu(bn1(. + bias2d)) -> zT[tv][c]
// ---------------------------------------------------------------------------
__global__ __launch_bounds__(512, 4) void k1_gcn(
    const float* __restrict__ x, const u16* __restrict__ atk, const u16* __restrict__ wt,
    const float* __restrict__ invadd, const float* __restrict__ bias2d,
    u16* __restrict__ zT)
{
  __shared__ __align__(16) u16 xaT[160 * 192];
  __shared__ float bias_l[1600];

  const int tid = threadIdx.x;
  const int tt = blockIdx.x, n = blockIdx.y;
  const int t0 = tt * 6;
  const int w = tid >> 6, l = tid & 63, lq = l & 15, g = l >> 4;
  const int ct = w & 3, h = w >> 2;
  const int co0 = ct * 16;

  for (int e = tid; e < 1600; e += 512) bias_l[e] = bias2d[n * 1600 + e];
  for (int e = tid; e < 10 * 192; e += 512) xaT[150 * 192 + e] = 0;  // tail rows -> 0

  // hoisted stage-1 B-frags: B[v][w] stored AT[w][v]
  bf16x8 Bf[3][2];
  #pragma unroll
  for (int k = 0; k < 3; ++k)
    #pragma unroll
    for (int nt = 0; nt < 2; ++nt)
      Bf[k][nt] = *(const bf16x8*)(atk + ((size_t)(n * 3 + k) * 32 + nt * 16 + lq) * 32 + g * 8);

  // stage-2 weight frags for OWN co-tile only: 6 frags = 24 VGPR
  bf16x8 wf1[6];
  #pragma unroll
  for (int kc = 0; kc < 6; ++kc)
    wf1[kc] = *(const bf16x8*)(wt + (co0 + lq) * 192 + kc * 32 + g * 8);

  // ---- stage 1: 24 M-tiles (6 t x 4 ci-tiles), wave w takes mt = w+8i ----
  f32x4 xc0, xc1;
  {
    const int mt = w;
    const int tl = mt >> 2, ci0 = (mt & 3) << 4;
    const float* xr = x + ((size_t)(n * 64 + ci0 + lq) * Tt + t0 + tl) * Vv;
    __builtin_memcpy(&xc0, xr + g * 8, 16);
    __builtin_memcpy(&xc1, xr + g * 8 + 4, 16);
  }
  #pragma unroll 1
  for (int i = 0; i < 3; ++i) {
    f32x4 xn0, xn1;
    if (i < 2) {
      const int mtn = w + 8 * (i + 1);
      const int tln = mtn >> 2, ci0n = (mtn & 3) << 4;
      const float* xrn = x + ((size_t)(n * 64 + ci0n + lq) * Tt + t0 + tln) * Vv;
      __builtin_memcpy(&xn0, xrn + g * 8, 16);
      __builtin_memcpy(&xn1, xrn + g * 8 + 4, 16);
    }
    const int mt = w + 8 * i;
    const int tl = mt >> 2, ci0 = (mt & 3) << 4;
    bf16x8 a;
    if (g < 3) {
      a[0] = (short)f2bu(xc0[0]); a[1] = (short)f2bu(xc0[1]);
      a[2] = (short)f2bu(xc0[2]); a[3] = (short)f2bu(xc0[3]);
      a[4] = (short)f2bu(xc1[0]); a[5] = (short)f2bu(xc1[1]);
      a[6] = (short)f2bu(xc1[2]); a[7] = (short)f2bu(xc1[3]);
    } else {
      a[0] = (short)f2bu(xc0[0]);     // element v=24
      a[1] = 0; a[2] = 0; a[3] = 0; a[4] = 0; a[5] = 0; a[6] = 0; a[7] = 0;
    }
    #pragma unroll
    for (int k = 0; k < 3; ++k)
      #pragma unroll
      for (int nt = 0; nt < 2; ++nt) {
        f32x4 acc = {0.f, 0.f, 0.f, 0.f};
        acc = __builtin_amdgcn_mfma_f32_16x16x32_bf16(a, Bf[k][nt], acc, 0, 0, 0);
        const int wcol = nt * 16 + lq;
        if (wcol < 25) {
          const int twl = tl * 25 + wcol;
          ushort4 s;
          s.x = f2bu(acc[0]); s.y = f2bu(acc[1]); s.z = f2bu(acc[2]); s.w = f2bu(acc[3]);
          const int byte = twl * 384 + ((k * 128 + ci0 * 2 + g * 8) ^ ((twl & 7) << 4));
          *(ushort4*)((char*)xaT + byte) = s;
        }
      }
    xc0 = xn0; xc1 = xn1;
  }
  __syncthreads();

  // ---- stage 2: wave = (ct, h); 5 uniform tw-tiles mt = h*5+j ----
  f32x4 acc[5];
  #pragma unroll
  for (int j = 0; j < 5; ++j) acc[j] = (f32x4){0.f, 0.f, 0.f, 0.f};

  #pragma unroll
  for (int kc = 0; kc < 6; ++kc) {
    #pragma unroll
    for (int j = 0; j < 5; ++j) {
      const int row = (h * 5 + j) * 16 + lq;
      const int byte = row * 384 + ((kc * 64 + g * 16) ^ ((row & 7) << 4));
      const bf16x8 Bv = *(const bf16x8*)((const char*)xaT + byte);
      acc[j] = __builtin_amdgcn_mfma_f32_16x16x32_bf16(wf1[kc], Bv, acc[j], 0, 0, 0);
    }
  }

  // ---- epilogue: bias + bn1 + relu -> zT[tv][c], ushort4 per lane ----
  const int c0 = co0 + g * 4;
  const f32x4 iv = *(const f32x4*)(invadd + c0);
  const f32x4 av = *(const f32x4*)(invadd + 64 + c0);
  #pragma unroll
  for (int j = 0; j < 5; ++j) {
    const int twl = (h * 5 + j) * 16 + lq;
    if (twl < 150) {
      const int wcol = twl % 25;
      const int tvg = tt * 150 + twl;
      ushort4 s;
      float z0 = (acc[j][0] + bias_l[(c0 + 0) * 25 + wcol]) * iv[0] + av[0];
      float z1 = (acc[j][1] + bias_l[(c0 + 1) * 25 + wcol]) * iv[1] + av[1];
      float z2 = (acc[j][2] + bias_l[(c0 + 2) * 25 + wcol]) * iv[2] + av[2];
      float z3 = (acc[j][3] + bias_l[(c0 + 3) * 25 + wcol]) * iv[3] + av[3];
      s.x = f2bu(fmaxf(z0, 0.f)); s.y = f2bu(fmaxf(z1, 0.f));
      s.z = f2bu(fmaxf(z2, 0.f)); s.w = f2bu(fmaxf(z3, 0.f));
      *(ushort4*)(zT + ((size_t)n * 7500 + tvg) * 64 + c0) = s;
    }
  }
}

// ---------------------------------------------------------------------------
// K2: fused TCN via MFMA. grid (25, 64), 512 threads = 8 waves, 12-t tile.
// Wave ownership: co-tile ct = w&3, M-half h = w>>2 (10 / 9 M-tiles).
// Per kc phase (2): preload 9 weight B-frags to VGPR (STATIC indexing —
// both kt loops fully unrolled, rule #20), then 9x10 pure
// {ds_read_b128 + MFMA} with zero global/scratch traffic.
// out = relu(bn2(conv) + x).
// ---------------------------------------------------------------------------
__global__ __launch_bounds__(512, 4) void k2_tcn(
    const u16* __restrict__ zT, const u16* __restrict__ w2t,
    const float* __restrict__ invadd, const float* __restrict__ x,
    float* __restrict__ out)
{
  __shared__ __align__(16) u16 win[512 * 64];

  const int tid = threadIdx.x;
  const int tt = blockIdx.x, n = blockIdx.y;
  const int t0 = tt * 12;
  const int w = tid >> 6, l = tid & 63, lq = l & 15, g = l >> 4;
  const int ct = w & 3, h = w >> 2;
  const int co0 = ct * 16;
  const int tvbase = t0 * 25 - 100;

  // stage window (512 rows x 64 ch), swizzled, 8 exact iters
  #pragma unroll
  for (int it = 0; it < 8; ++it) {
    const int f = tid + it * 512;
    const int lrow = f >> 3, c16 = f & 7;
    const int tv = tvbase + lrow;
    bf16x8 val = {0, 0, 0, 0, 0, 0, 0, 0};
    if (tv >= 0 && tv < 7500)
      val = *(const bf16x8*)(zT + ((size_t)n * 7500 + tv) * 64 + c16 * 8);
    const int byte = lrow * 128 + ((c16 * 16) ^ ((lrow & 7) << 4));
    *(bf16x8*)((char*)win + byte) = val;
  }
  __syncthreads();

  const int nj = h ? 9 : 10;          // M-tiles: h=0 -> 0..9, h=1 -> 10..18
  f32x4 acc[10];
  #pragma unroll
  for (int j = 0; j < 10; ++j) acc[j] = (f32x4){0.f, 0.f, 0.f, 0.f};

  #pragma unroll 1
  for (int kc = 0; kc < 2; ++kc) {
    bf16x8 wf[9];
    #pragma unroll
    for (int kt = 0; kt < 9; ++kt)
      wf[kt] = *(const bf16x8*)(w2t + (size_t)(kt * 64 + co0 + lq) * 64 + kc * 32 + g * 8);
    #pragma unroll
    for (int kt = 0; kt < 9; ++kt) {     // FULLY unrolled: wf[kt] static -> VGPR
      #pragma unroll
      for (int j = 0; j < 10; ++j) {
        if (j < nj) {
          const int mt = h * 10 + j;
          const int lrow = mt * 16 + lq + kt * 25;
          const int byte = lrow * 128 + ((kc * 64 + g * 16) ^ ((lrow & 7) << 4));
          const bf16x8 Av = *(const bf16x8*)((const char*)win + byte);
          acc[j] = __builtin_amdgcn_mfma_f32_16x16x32_bf16(Av, wf[kt], acc[j], 0, 0, 0);
        }
      }
    }
  }

  // epilogue: +bn2 + residual + relu
  const float i2 = invadd[128 + co0 + lq];
  const float a2 = invadd[192 + co0 + lq];
  #pragma unroll
  for (int j = 0; j < 10; ++j) {
    if (j < nj) {
      const int mt = h * 10 + j;
      const int tvl0 = mt * 16 + g * 4;
      if (tvl0 < 300) {
        const size_t base = (size_t)(n * 64 + co0 + lq) * 7500 + t0 * 25 + tvl0;
        const f32x4 xv = *(const f32x4*)(x + base);
        f32x4 o;
        #pragma unroll
        for (int r = 0; r < 4; ++r)
          o[r] = fmaxf(acc[j][r] * i2 + a2 + xv[r], 0.f);
        *(f32x4*)(out + base) = o;
      }
    }
  }
}

} // namespace

extern "C" void kernel_launch(void* const* d_in, const int* in_sizes, int n_in,
                              void* d_out, int out_size, void* d_ws, size_t ws_size,
                              hipStream_t stream)
{
  const float* x  = (const float*)d_in[0];
  const float* A  = (const float*)d_in[1];
  const float* Wc = (const float*)d_in[2];
  const float* bc = (const float*)d_in[3];
  const float* g1 = (const float*)d_in[4];
  const float* b1 = (const float*)d_in[5];
  const float* m1 = (const float*)d_in[6];
  const float* v1 = (const float*)d_in[7];
  const float* tw = (const float*)d_in[8];
  const float* tb = (const float*)d_in[9];
  const float* g2 = (const float*)d_in[10];
  const float* b2 = (const float*)d_in[11];
  const float* m2 = (const float*)d_in[12];
  const float* v2 = (const float*)d_in[13];
  float* out = (float*)d_out;

  char* ws = (char*)d_ws;
  u16*   zT     = (u16*)(ws);                        // 61,440,000 B
  u16*   atk    = (u16*)(ws + 61440000);             //    393,216 B
  u16*   wt     = (u16*)(ws + 61833216);             //     24,576 B
  u16*   w2t    = (u16*)(ws + 61857792);             //     73,728 B
  float* invadd = (float*)(ws + 61931520);           //      1,024 B
  float* bias2d = (float*)(ws + 61932544);           //    409,600 B

  prep<<<dim3(74), dim3(256), 0, stream>>>(A, Wc, bc, g1, b1, m1, v1, tw, tb,
                                           g2, b2, m2, v2, atk, wt, w2t, invadd, bias2d,
                                           out + 30720000);
  k1_gcn<<<dim3(50, 64), dim3(512), 0, stream>>>(x, atk, wt, invadd, bias2d, zT);
  k2_tcn<<<dim3(25, 64), dim3(512), 0, stream>>>(zT, w2t, invadd, x, out);
}